// Round 4
// baseline (456.556 us; speedup 1.0000x reference)
//
#include <hip/hip_runtime.h>
#include <hip/hip_bf16.h>

typedef __attribute__((ext_vector_type(8))) short short8;     // 8 bf16 / 16B
typedef __attribute__((ext_vector_type(4))) float f32x4;
typedef __attribute__((ext_vector_type(4))) unsigned int uint4v;

#define XSTRIDE 1856          // 29*64 floats per edge
#define CCH 64
// padded effective-weight layout (bf16 elems): blk0 [512][448], blk1 [768][768], blk2 [640][640]
#define OFF1 229376
#define OFF2 819200
#define WTOT 1228800

__constant__ int d_TO_M[29] = {0,2,6,11,16,21,26, 3,7,12,17,22,27, 1,5,10,15,20,25,
                               8,13,18,23,28, 4,9,14,19,24};

__device__ __forceinline__ short f2bf(float f) {
    __hip_bfloat16 h = __float2bfloat16(f);
    return __builtin_bit_cast(short, h);
}

__device__ __forceinline__ void load16_lds(const void* g, void* l) {
    __builtin_amdgcn_global_load_lds((const __attribute__((address_space(1))) unsigned int*)g,
                                     (__attribute__((address_space(3))) unsigned int*)l, 16, 0, 0);
}

// ---------------- pass 1: effective bf16 weights (blk0 zero-padded to 512 rows) -------------
__global__ __launch_bounds__(256) void prep_weights(const float* __restrict__ W0,
                                                    const float* __restrict__ W1,
                                                    const float* __restrict__ W2,
                                                    short* __restrict__ ws) {
    int idx = blockIdx.x * 256 + threadIdx.x;
    if (idx < OFF1) {                       // [512][448], rows >=448 are zero pad
        ws[idx] = (idx < 448 * 448) ? f2bf(W0[idx]) : (short)0;
        return;
    }
    if (idx < OFF2) {
        int i = idx - OFF1;
        int n = i / 768, k = i % 768;
        int no = n / 384, ni = n % 384;
        int ki = k % 384;
        float v;
        if (no == (k / 384)) v =  W1[ni * 384 + ki];
        else if (no == 0)    v = -W1[(384 + ni) * 384 + ki];
        else                 v =  W1[(384 + ni) * 384 + ki];
        ws[idx] = f2bf(v);
        return;
    }
    if (idx < WTOT) {
        int i = idx - OFF2;
        int n = i / 640, k = i % 640;
        int no = n / 320, ni = n % 320;
        int ki = k % 320;
        float v;
        if (no == (k / 320)) v =  W2[ni * 320 + ki];
        else if (no == 0)    v = -W2[(320 + ni) * 320 + ki];
        else                 v =  W2[(320 + ni) * 320 + ki];
        ws[idx] = f2bf(v);
    }
}

// ---------------- pass 2: pack x -> bf16 [etile][g][128 edges][64 ch] ------------------------
// block = (etile, g). Reads coalesced 256B/edge-row; writes contiguous 1KB/wave.
__global__ __launch_bounds__(256) void pack_x(const float* __restrict__ x,
                                              short* __restrict__ pA, int E) {
    int b = blockIdx.x;
    int etile = b / 29, g = b % 29;
    int ebase = etile * 128;
    size_t dst = (size_t)b * (128 * 64);
#pragma unroll
    for (int j = 0; j < 4; ++j) {
        int flat = j * 256 + threadIdx.x;       // [0,1024): 128 edges x 8 ch-chunks
        int ei = flat >> 3, ch0 = (flat & 7) * 8;
        int e = ebase + ei;
        short8 hv;
        if (e < E) {
            const float* p = x + (size_t)e * XSTRIDE + g * 64 + ch0;
            f32x4 v0 = *(const f32x4*)p, v1 = *(const f32x4*)(p + 4);
#pragma unroll
            for (int q = 0; q < 4; ++q) { hv[q] = f2bf(v0[q]); hv[4 + q] = f2bf(v1[q]); }
        } else {
            hv = short8{0,0,0,0,0,0,0,0};       // zero-pad tail edges
        }
        *(short8*)&pA[dst + (size_t)ei * 64 + ch0] = hv;
    }
}

// ---------------- pass 3: GEMM, A/B via global_load_lds, counted-vmcnt 2-phase ---------------
// 128(edges) x 128(cols), BK=64 (= one full g-row), 4 waves x (64x64), mfma 16x16x32 bf16.
// LDS tiles [128 rows][64 bf16] = 128B rows, 8x16B chunks; source-chunk XOR swizzle
// (slot s holds global chunk s^(row&7)) -> ds_read_b128 frags are conflict-free.
__global__ __launch_bounds__(256, 2) void so2_gemm_p(const short* __restrict__ pA,
                                                     const float* __restrict__ b0,
                                                     const short* __restrict__ wsW,
                                                     float* __restrict__ out,
                                                     int E, int nwg) {
    // bijective XCD chunk swizzle: one etile's 15 n-tiles share an XCD's L2
    int orig = blockIdx.x;
    int q8 = nwg >> 3, r8 = nwg & 7;
    int xcd = orig & 7, pos = orig >> 3;
    int wgid = (xcd < r8 ? xcd * (q8 + 1) : r8 * (q8 + 1) + (xcd - r8) * q8) + pos;

    int etile = wgid / 15;
    int ncol  = wgid % 15;
    int blk, ntl;
    if (ncol < 4)       { blk = 0; ntl = ncol; }
    else if (ncol < 10) { blk = 1; ntl = ncol - 4; }
    else                { blk = 2; ntl = ncol - 10; }
    const int Kb     = (blk == 0) ? 448 : (blk == 1) ? 768 : 640;
    const int ksteps = Kb >> 6;                                     // 7 / 12 / 10
    const int kbase  = (blk == 0) ? 0 : (blk == 1) ? 7 : 19;
    const int nrows  = (blk == 0) ? 7 : (blk == 1) ? 12 : 10;
    const long woff  = (blk == 0) ? 0 : (blk == 1) ? (long)OFF1 : (long)OFF2;
    const short* Wb  = wsW + woff;
    const int n0 = ntl * 128;

    __shared__ short Alds[2][128 * 64];   // 16 KB each
    __shared__ short Blds[2][128 * 64];   // total 64 KB

    const int tid  = threadIdx.x;
    const int w    = tid >> 6, lane = tid & 63;
    const int wr   = w >> 1,   wc   = w & 1;
    const int lrow = lane & 15, lk  = lane >> 4;
    const int ebase = etile * 128;

    const int lr = lane >> 3;             // staging: row-within-8, also == row&7
    const int cs = (lane & 7) ^ lr;       // swizzled source chunk

    f32x4 acc[4][4] = {};

    auto stageA = [&](int kt, int pb) {
        int g = d_TO_M[kbase + kt];
        const short* src = pA + ((size_t)(etile * 29 + g)) * (128 * 64);
#pragma unroll
        for (int j = 0; j < 4; ++j) {
            int rb = w * 32 + j * 8;
            load16_lds(src + (size_t)(rb + lr) * 64 + cs * 8,
                       (char*)&Alds[pb][rb * 64] + lane * 16);
        }
    };
    auto stageB = [&](int kt, int pb) {
        const short* src = Wb + (size_t)kt * 64;
#pragma unroll
        for (int j = 0; j < 4; ++j) {
            int rb = w * 32 + j * 8;
            load16_lds(src + (size_t)(n0 + rb + lr) * Kb + cs * 8,
                       (char*)&Blds[pb][rb * 64] + lane * 16);
        }
    };
    auto compute = [&](int pb) {
#pragma unroll
        for (int ks = 0; ks < 2; ++ks) {
            short8 af[4], bf[4];
#pragma unroll
            for (int mf = 0; mf < 4; ++mf) {
                int row = wr * 64 + mf * 16 + lrow;
                int s = (ks * 4 + lk) ^ (lrow & 7);
                af[mf] = *(const short8*)&Alds[pb][row * 64 + s * 8];
            }
#pragma unroll
            for (int nf = 0; nf < 4; ++nf) {
                int row = wc * 64 + nf * 16 + lrow;
                int s = (ks * 4 + lk) ^ (lrow & 7);
                bf[nf] = *(const short8*)&Blds[pb][row * 64 + s * 8];
            }
#pragma unroll
            for (int mf = 0; mf < 4; ++mf)
#pragma unroll
                for (int nf = 0; nf < 4; ++nf)
                    acc[mf][nf] = __builtin_amdgcn_mfma_f32_16x16x32_bf16(af[mf], bf[nf], acc[mf][nf], 0, 0, 0);
        }
    };

    stageA(0, 0); stageB(0, 0);
    asm volatile("s_waitcnt vmcnt(0)" ::: "memory");
    __builtin_amdgcn_s_barrier();
    __builtin_amdgcn_sched_barrier(0);

    int pb = 0;
    for (int kt = 0; kt < ksteps; ++kt, pb ^= 1) {
        if (kt + 1 < ksteps) { stageA(kt + 1, pb ^ 1); stageB(kt + 1, pb ^ 1); }
        compute(pb);                                   // MFMA covers the in-flight loads
        asm volatile("s_waitcnt vmcnt(0)" ::: "memory");  // next tile landed
        __builtin_amdgcn_s_barrier();
        __builtin_amdgcn_sched_barrier(0);
    }

    // epilogue: wave's 64 cols = output m-row (ntl*2 + wc); store to lp-row TO_M[...]
    int mrow_l = ntl * 2 + wc;
    if (mrow_l < nrows) {
        int lp = d_TO_M[kbase + mrow_l];
        float* op = out + (size_t)lp * CCH;
#pragma unroll
        for (int nf = 0; nf < 4; ++nf) {
            int c = nf * 16 + lrow;
            float bias = 0.f;
            if (blk == 0) bias = b0[mrow_l * 64 + c];
#pragma unroll
            for (int mf = 0; mf < 4; ++mf) {
                int e0 = ebase + wr * 64 + mf * 16 + lk * 4;
#pragma unroll
                for (int j = 0; j < 4; ++j) {
                    int e = e0 + j;
                    if (e < E) op[(size_t)e * XSTRIDE + c] = acc[mf][nf][j] + bias;
                }
            }
        }
    }
}

// ---------------- fallback (R1 structure, reg-staged f32 A) if ws can't hold packed A -------
__global__ __launch_bounds__(256) void so2_gemm_fb(const float* __restrict__ x,
                                                   const float* __restrict__ b0,
                                                   const short* __restrict__ wsW,
                                                   float* __restrict__ out,
                                                   int E, int nwg) {
    int orig = blockIdx.x;
    int q8 = nwg >> 3, r8 = nwg & 7;
    int xcd = orig & 7, pos = orig >> 3;
    int wgid = (xcd < r8 ? xcd * (q8 + 1) : r8 * (q8 + 1) + (xcd - r8) * q8) + pos;
    int etile = wgid / 15, ncol = wgid % 15;
    int blk, ntl;
    if (ncol < 4)       { blk = 0; ntl = ncol; }
    else if (ncol < 10) { blk = 1; ntl = ncol - 4; }
    else                { blk = 2; ntl = ncol - 10; }
    const int Kb     = (blk == 0) ? 448 : (blk == 1) ? 768 : 640;
    const int ksteps = Kb >> 6;
    const int kbase  = (blk == 0) ? 0 : (blk == 1) ? 7 : 19;
    const int nrows  = (blk == 0) ? 7 : (blk == 1) ? 12 : 10;
    const long woff  = (blk == 0) ? 0 : (blk == 1) ? (long)OFF1 : (long)OFF2;
    const short* Wb  = wsW + woff;

    __shared__ short Alds[128 * 72];
    __shared__ short Blds[128 * 72];
    const int tid = threadIdx.x;
    const int w = tid >> 6, lane = tid & 63;
    const int wr = w >> 1, wc = w & 1;
    const int lrow = lane & 15, lk = lane >> 4;
    const int ebase = etile * 128;
    f32x4 acc[4][4] = {};

    for (int kt = 0; kt < ksteps; ++kt) {
        int g = d_TO_M[kbase + kt];
        __syncthreads();
#pragma unroll
        for (int i = 0; i < 4; ++i) {
            int item = i * 256 + tid;
            int row = item >> 3, ch0 = (item & 7) << 3;
            int e = ebase + row;
            f32x4 a0{0,0,0,0}, a1{0,0,0,0};
            if (e < E) {
                const float* p = x + (size_t)e * XSTRIDE + (size_t)g * CCH + ch0;
                a0 = *(const f32x4*)p; a1 = *(const f32x4*)(p + 4);
            }
            short8 hv;
#pragma unroll
            for (int q = 0; q < 4; ++q) { hv[q] = f2bf(a0[q]); hv[4 + q] = f2bf(a1[q]); }
            *(short8*)&Alds[row * 72 + ch0] = hv;
            int n = ntl * 128 + row;
            uint4v bv = (n < Kb) ? *(const uint4v*)(Wb + (size_t)n * Kb + kt * 64 + ch0)
                                 : uint4v{0,0,0,0};
            *(uint4v*)&Blds[row * 72 + ch0] = bv;
        }
        __syncthreads();
#pragma unroll
        for (int ks = 0; ks < 2; ++ks) {
            short8 af[4], bf[4];
#pragma unroll
            for (int mf = 0; mf < 4; ++mf)
                af[mf] = *(short8*)&Alds[(wr * 64 + mf * 16 + lrow) * 72 + ks * 32 + lk * 8];
#pragma unroll
            for (int nf = 0; nf < 4; ++nf)
                bf[nf] = *(short8*)&Blds[(wc * 64 + nf * 16 + lrow) * 72 + ks * 32 + lk * 8];
#pragma unroll
            for (int mf = 0; mf < 4; ++mf)
#pragma unroll
                for (int nf = 0; nf < 4; ++nf)
                    acc[mf][nf] = __builtin_amdgcn_mfma_f32_16x16x32_bf16(af[mf], bf[nf], acc[mf][nf], 0, 0, 0);
        }
    }

    int mrow_l = ntl * 2 + wc;
    if (mrow_l < nrows) {
        int lp = d_TO_M[kbase + mrow_l];
        float* op = out + (size_t)lp * CCH;
#pragma unroll
        for (int nf = 0; nf < 4; ++nf) {
            int c = nf * 16 + lrow;
            float bias = (blk == 0) ? b0[mrow_l * 64 + c] : 0.f;
#pragma unroll
            for (int mf = 0; mf < 4; ++mf) {
                int e0 = ebase + wr * 64 + mf * 16 + lk * 4;
#pragma unroll
                for (int j = 0; j < 4; ++j) {
                    int e = e0 + j;
                    if (e < E) op[(size_t)e * XSTRIDE + c] = acc[mf][nf][j] + bias;
                }
            }
        }
    }
}

extern "C" void kernel_launch(void* const* d_in, const int* in_sizes, int n_in,
                              void* d_out, int out_size, void* d_ws, size_t ws_size,
                              hipStream_t stream) {
    const float* x_emb = (const float*)d_in[0];
    // d_in[1] = x_edge: unused by the reference
    const float* W0 = (const float*)d_in[2];
    const float* b0 = (const float*)d_in[3];
    const float* W1 = (const float*)d_in[4];
    const float* W2 = (const float*)d_in[5];
    float* out = (float*)d_out;
    short* ws  = (short*)d_ws;

    const int E = in_sizes[0] / (29 * CCH);
    const int etiles = (E + 127) / 128;
    const int nwg = etiles * 15;

    prep_weights<<<(WTOT + 255) / 256, 256, 0, stream>>>(W0, W1, W2, ws);

    const size_t packA_elems = (size_t)etiles * 29 * 128 * 64;
    const size_t need_bytes = ((size_t)WTOT + packA_elems) * sizeof(short);

    if (ws_size >= need_bytes) {
        short* pA = ws + WTOT;
        pack_x<<<etiles * 29, 256, 0, stream>>>(x_emb, pA, E);
        so2_gemm_p<<<nwg, 256, 0, stream>>>(pA, b0, (const short*)ws, out, E, nwg);
    } else {
        so2_gemm_fb<<<nwg, 256, 0, stream>>>(x_emb, b0, (const short*)ws, out, E, nwg);
    }
}

// Round 5
// 452.713 us; speedup vs baseline: 1.0085x; 1.0085x over previous
//
#include <hip/hip_runtime.h>
#include <hip/hip_bf16.h>

typedef __attribute__((ext_vector_type(8))) short short8;     // 8 bf16 / 16B
typedef __attribute__((ext_vector_type(4))) float f32x4;

#define XSTRIDE 1856          // 29*64 floats per edge
#define CCH 64
// padded effective-weight layout (bf16): blk0 [512][448], blk1 [768][768], blk2 [640][640]
#define OFF1 229376
#define OFF2 819200
#define WTOT 1228800

__constant__ int d_TO_M[29] = {0,2,6,11,16,21,26, 3,7,12,17,22,27, 1,5,10,15,20,25,
                               8,13,18,23,28, 4,9,14,19,24};

__device__ __forceinline__ short f2bf(float f) {
    __hip_bfloat16 h = __float2bfloat16(f);
    return __builtin_bit_cast(short, h);
}

__device__ __forceinline__ void load16_lds(const void* g, void* l) {
    __builtin_amdgcn_global_load_lds((const __attribute__((address_space(1))) unsigned int*)g,
                                     (__attribute__((address_space(3))) unsigned int*)l, 16, 0, 0);
}

// ---------------- pass 1: effective bf16 weights (blk0 zero-padded to 512 rows) -------------
__global__ __launch_bounds__(256) void prep_weights(const float* __restrict__ W0,
                                                    const float* __restrict__ W1,
                                                    const float* __restrict__ W2,
                                                    short* __restrict__ ws) {
    int idx = blockIdx.x * 256 + threadIdx.x;
    if (idx < OFF1) {                       // [512][448], rows >=448 zero pad
        ws[idx] = (idx < 448 * 448) ? f2bf(W0[idx]) : (short)0;
        return;
    }
    if (idx < OFF2) {
        int i = idx - OFF1;
        int n = i / 768, k = i % 768;
        int no = n / 384, ni = n % 384;
        int ki = k % 384;
        float v;
        if (no == (k / 384)) v =  W1[ni * 384 + ki];
        else if (no == 0)    v = -W1[(384 + ni) * 384 + ki];
        else                 v =  W1[(384 + ni) * 384 + ki];
        ws[idx] = f2bf(v);
        return;
    }
    if (idx < WTOT) {
        int i = idx - OFF2;
        int n = i / 640, k = i % 640;
        int no = n / 320, ni = n % 320;
        int ki = k % 320;
        float v;
        if (no == (k / 320)) v =  W2[ni * 320 + ki];
        else if (no == 0)    v = -W2[(320 + ni) * 320 + ki];
        else                 v =  W2[(320 + ni) * 320 + ki];
        ws[idx] = f2bf(v);
    }
}

// ---------------- pass 2: fused GEMM, counted-vmcnt pipeline -------------------------------
// 128(edges) x 128(cols), BK=32, 4 waves x (64x64), mfma 16x16x32 bf16.
// A staged as f32 via global_load_lds, triple-buffered (depth-2 prefetch);
// B staged as bf16, double-buffered (depth-1, L2-hot). Never drain vmcnt to 0
// in steady state: s_waitcnt vmcnt(4) leaves next A-tile's 4 loads in flight
// across the barrier. f32->bf16 conversion happens at fragment-read time.
// XOR chunk swizzles: A slot c holds global chunk c^(row&7) (16B=4 floats);
// B slot c holds global chunk c^((row>>1)&3) (16B=8 bf16) -> frag reads 2-way (free).
__global__ __launch_bounds__(256, 2) void so2_gemm_f(const float* __restrict__ x,
                                                     const float* __restrict__ b0,
                                                     const short* __restrict__ wsW,
                                                     float* __restrict__ out,
                                                     int E, int nwg) {
    // bijective XCD chunk swizzle: one etile's 15 n-tiles share an XCD's L2
    int orig = blockIdx.x;
    int q8 = nwg >> 3, r8 = nwg & 7;
    int xcd = orig & 7, pos = orig >> 3;
    int wgid = (xcd < r8 ? xcd * (q8 + 1) : r8 * (q8 + 1) + (xcd - r8) * q8) + pos;

    int etile = wgid / 15;
    int ncol  = wgid % 15;
    int blk, ntl;
    if (ncol < 4)       { blk = 0; ntl = ncol; }
    else if (ncol < 10) { blk = 1; ntl = ncol - 4; }
    else                { blk = 2; ntl = ncol - 10; }
    const int Kb     = (blk == 0) ? 448 : (blk == 1) ? 768 : 640;
    const int ksteps = Kb >> 5;                                     // 14 / 24 / 20 (even)
    const int kbase  = (blk == 0) ? 0 : (blk == 1) ? 7 : 19;
    const int nrows  = (blk == 0) ? 7 : (blk == 1) ? 12 : 10;
    const long woff  = (blk == 0) ? 0 : (blk == 1) ? (long)OFF1 : (long)OFF2;
    const short* Wb  = wsW + woff;
    const int n0 = ntl * 128;

    __shared__ float Af[3][128 * 32];   // 16 KB x3: A tile f32 [128 edges][32 ch]
    __shared__ short Bf[2][128 * 32];   //  8 KB x2: B tile bf16 [128 n][32 k]

    const int tid  = threadIdx.x;
    const int w    = tid >> 6, lane = tid & 63;
    const int wr   = w >> 1,   wc   = w & 1;
    const int lrow = lane & 15, lk  = lane >> 4;
    const int ebase = etile * 128;

    // staging addressing
    const int lr = lane >> 3;                       // A: row-within-8
    const int ca = (lane & 7) ^ lr;                 // A: swizzled src chunk (4 floats)
    const int rbq = lane >> 2;                      // B: row-within-16
    const int cb = (lane & 3) ^ ((lane >> 3) & 3);  // B: swizzled src chunk (8 bf16)

    f32x4 acc[4][4] = {};

    auto stageA = [&](int kt, int pb) {
        int g = d_TO_M[kbase + (kt >> 1)];
        const float* src = x + (size_t)g * CCH + (kt & 1) * 32 + ca * 4;
#pragma unroll
        for (int j = 0; j < 4; ++j) {
            int rb = w * 32 + j * 8;
            int e = ebase + rb + lr;
            if (e >= E) e = E - 1;                  // clamp: uniform vmcnt, rows never stored
            load16_lds(src + (size_t)e * XSTRIDE,
                       (char*)&Af[pb][rb * 32] + lane * 16);
        }
    };
    auto stageB = [&](int kt, int pb) {
        const short* src = Wb + (size_t)kt * 32 + cb * 8;
#pragma unroll
        for (int j = 0; j < 2; ++j) {
            int rb = w * 32 + j * 16;
            int n = n0 + rb + rbq;                  // always in-bounds (padded weights)
            load16_lds(src + (size_t)n * Kb,
                       (char*)&Bf[pb][rb * 32] + lane * 16);
        }
    };
    auto compute = [&](int pa, int pbb) {
        short8 af[4], bf[4];
#pragma unroll
        for (int mf = 0; mf < 4; ++mf) {
            int r = wr * 64 + mf * 16 + lrow;
            int s0 = (2 * lk) ^ (lrow & 7);
            int s1 = (2 * lk + 1) ^ (lrow & 7);
            f32x4 lo = *(const f32x4*)&Af[pa][r * 32 + s0 * 4];
            f32x4 hi = *(const f32x4*)&Af[pa][r * 32 + s1 * 4];
            short8 v;
#pragma unroll
            for (int j = 0; j < 4; ++j) { v[j] = f2bf(lo[j]); v[4 + j] = f2bf(hi[j]); }
            af[mf] = v;
        }
#pragma unroll
        for (int nf = 0; nf < 4; ++nf) {
            int r = wc * 64 + nf * 16 + lrow;
            int s = lk ^ ((lrow >> 1) & 3);
            bf[nf] = *(const short8*)&Bf[pbb][r * 32 + s * 8];
        }
#pragma unroll
        for (int mf = 0; mf < 4; ++mf)
#pragma unroll
            for (int nf = 0; nf < 4; ++nf)
                acc[mf][nf] = __builtin_amdgcn_mfma_f32_16x16x32_bf16(af[mf], bf[nf], acc[mf][nf], 0, 0, 0);
    };

    // prologue: queue = A0[4], B0[2], A1[4]; wait oldest 6 (A0,B0), keep A1 in flight
    stageA(0, 0);
    stageB(0, 0);
    stageA(1, 1);
    asm volatile("s_waitcnt vmcnt(4)" ::: "memory");
    __builtin_amdgcn_s_barrier();
    __builtin_amdgcn_sched_barrier(0);

    int pa = 0;                                     // A buf holding tile kt
    for (int kt = 0; kt < ksteps; ++kt) {
        int pa1 = pa + 1; if (pa1 == 3) pa1 = 0;
        int pa2 = pa1 + 1; if (pa2 == 3) pa2 = 0;
        // issue order matters for vmcnt accounting: B(kt+1) BEFORE A(kt+2)
        if (kt + 1 < ksteps) stageB(kt + 1, (kt + 1) & 1);
        __builtin_amdgcn_sched_barrier(0);          // pin B issues ahead of A issues
        if (kt + 2 < ksteps) stageA(kt + 2, pa2);
        compute(pa, kt & 1);
        if (kt + 2 < ksteps) {
            // queue: A(kt+1)[4], B(kt+1)[2], A(kt+2)[4] -> retire oldest 6
            asm volatile("s_waitcnt vmcnt(4)" ::: "memory");
        } else if (kt + 1 < ksteps) {
            asm volatile("s_waitcnt vmcnt(0)" ::: "memory");
        }
        __builtin_amdgcn_s_barrier();
        __builtin_amdgcn_sched_barrier(0);
        pa = pa1;
    }

    // epilogue: wave's 64 cols = output m-row (ntl*2 + wc); store to lp-row TO_M[...]
    int mrow_l = ntl * 2 + wc;
    if (mrow_l < nrows) {
        int lp = d_TO_M[kbase + mrow_l];
        float* op = out + (size_t)lp * CCH;
#pragma unroll
        for (int nf = 0; nf < 4; ++nf) {
            int c = nf * 16 + lrow;
            float bias = 0.f;
            if (blk == 0) bias = b0[mrow_l * 64 + c];
#pragma unroll
            for (int mf = 0; mf < 4; ++mf) {
                int e0 = ebase + wr * 64 + mf * 16 + lk * 4;
#pragma unroll
                for (int j = 0; j < 4; ++j) {
                    int e = e0 + j;
                    if (e < E) op[(size_t)e * XSTRIDE + c] = acc[mf][nf][j] + bias;
                }
            }
        }
    }
}

extern "C" void kernel_launch(void* const* d_in, const int* in_sizes, int n_in,
                              void* d_out, int out_size, void* d_ws, size_t ws_size,
                              hipStream_t stream) {
    const float* x_emb = (const float*)d_in[0];
    // d_in[1] = x_edge: unused by the reference
    const float* W0 = (const float*)d_in[2];
    const float* b0 = (const float*)d_in[3];
    const float* W1 = (const float*)d_in[4];
    const float* W2 = (const float*)d_in[5];
    float* out = (float*)d_out;
    short* ws  = (short*)d_ws;     // 2.46 MB effective bf16 weights

    const int E = in_sizes[0] / (29 * CCH);
    const int etiles = (E + 127) / 128;
    const int nwg = etiles * 15;

    prep_weights<<<(WTOT + 255) / 256, 256, 0, stream>>>(W0, W1, W2, ws);
    so2_gemm_f<<<nwg, 256, 0, stream>>>(x_emb, b0, (const short*)ws, out, E, nwg);
}